// Round 1
// baseline (265.638 us; speedup 1.0000x reference)
//
#include <hip/hip_runtime.h>
#include <math.h>

#define NJ 10        // odd powers x^1..x^19
#define CAT 450
#define ESTRIDE 456
#define X0f 3.0f

struct Poly { float c[NJ]; };

#define FMA4(A,S,W) do { (A).x = fmaf((S),(W).x,(A).x); (A).y = fmaf((S),(W).y,(A).y); \
                         (A).z = fmaf((S),(W).z,(A).z); (A).w = fmaf((S),(W).w,(A).w); } while(0)

// ---------------- K0: repack Wc -> [3][464][32] (zero-padded c), clsW1 -> [450][128] ----------------
__global__ __launch_bounds__(256) void k_repack(const float* __restrict__ Wc,
                                                const float* __restrict__ W1,
                                                float* __restrict__ WcT,
                                                float* __restrict__ W1T) {
    int tid = blockIdx.x * 256 + threadIdx.x;
    int stride = gridDim.x * 256;
    for (int idx = tid; idx < 3 * 464 * 32; idx += stride) {
        int i = idx / (464 * 32);
        int rem = idx - i * 464 * 32;
        int c = rem >> 5;
        int h = rem & 31;
        WcT[idx] = (c < CAT) ? Wc[(i * 32 + h) * CAT + c] : 0.f;
    }
    for (int idx = tid; idx < CAT * 128; idx += stride) {
        int c = idx >> 7;
        int k = idx & 127;
        W1T[idx] = W1[k * CAT + c];
    }
}

// ---------------- K1: encoders. 8 batch rows per block. ----------------
__global__ __launch_bounds__(256) void k_enc(
    const float* __restrict__ x0, const float* __restrict__ x1, const float* __restrict__ x2,
    const float* __restrict__ eW0, const float* __restrict__ eb0,
    const float* __restrict__ eW1, const float* __restrict__ eb1,
    const float* __restrict__ eW2, const float* __restrict__ eb2,
    float* __restrict__ wsEnc) {
    __shared__ float xs[8][424];  // seg0 @0 (300), seg1 @304 (74), seg2 @384 (35)
    int tid = threadIdx.x;
    int b0 = blockIdx.x * 8;
    for (int idx = tid; idx < 8 * 300; idx += 256) { int b = idx / 300, d = idx - b * 300; xs[b][d]       = x0[(b0 + b) * 300 + d]; }
    for (int idx = tid; idx < 8 * 74;  idx += 256) { int b = idx / 74,  d = idx - b * 74;  xs[b][304 + d] = x1[(b0 + b) * 74  + d]; }
    for (int idx = tid; idx < 8 * 35;  idx += 256) { int b = idx / 35,  d = idx - b * 35;  xs[b][384 + d] = x2[(b0 + b) * 35  + d]; }
    __syncthreads();
    for (int t = tid; t < 8 * CAT; t += 256) {
        int b = t / CAT, e = t - b * CAT;
        float acc;
        if (e < 150) {
            acc = eb0[e];
            const float4* w  = (const float4*)(eW0 + e * 300);
            const float4* xr = (const float4*)(&xs[b][0]);
            #pragma unroll 5
            for (int d = 0; d < 75; ++d) {
                float4 wv = w[d], xv = xr[d];
                acc = fmaf(wv.x, xv.x, acc); acc = fmaf(wv.y, xv.y, acc);
                acc = fmaf(wv.z, xv.z, acc); acc = fmaf(wv.w, xv.w, acc);
            }
        } else if (e < 300) {
            int e1 = e - 150;
            acc = eb1[e1];
            const float2* w  = (const float2*)(eW1 + e1 * 74);
            const float2* xr = (const float2*)(&xs[b][304]);
            #pragma unroll
            for (int d = 0; d < 37; ++d) {
                float2 wv = w[d], xv = xr[d];
                acc = fmaf(wv.x, xv.x, acc); acc = fmaf(wv.y, xv.y, acc);
            }
        } else {
            int e2 = e - 300;
            acc = eb2[e2];
            const float* w = eW2 + e2 * 35;
            #pragma unroll
            for (int d = 0; d < 35; ++d) acc = fmaf(w[d], xs[b][384 + d], acc);
        }
        wsEnc[(b0 + b) * ESTRIDE + e] = acc;
    }
}

// ---------------- K2: attention branch via factorized tanh polynomial ----------------
// block = (4 batch rows) x (1 branch). 320 threads.
__global__ __launch_bounds__(320) void k_attn(
    const float* __restrict__ wsEnc,
    const float* __restrict__ WcT,    // [3][464][32]
    const float* __restrict__ affw,   // [3]
    const float* __restrict__ Ww,     // [3][32]
    const float* __restrict__ Wh,     // [3][32]
    float* __restrict__ wsFeats,
    Poly pc) {
    __shared__ float feat[4][512];     // enc row, zero-padded beyond 450
    __shared__ float Gp[40][68];       // g-powers, one 64-c chunk; stride 68 kills bank conflicts
    __shared__ float Mm[40][32];       // M[b*10+J][h]
    __shared__ float wW[32], wH[32];
    __shared__ unsigned smaxu[4];

    int tid = threadIdx.x;
    int b0 = blockIdx.x * 4;
    int i  = blockIdx.y;
    float aff = affw[i];

    if (tid < 4)  smaxu[tid] = 0u;
    if (tid < 32) { wW[tid] = Ww[i * 32 + tid]; wH[tid] = Wh[i * 32 + tid]; }
    __syncthreads();
    for (int idx = tid; idx < 4 * 512; idx += 320) {
        int b = idx >> 9, c = idx & 511;
        float v = (c < CAT) ? wsEnc[(b0 + b) * ESTRIDE + c] : 0.f;
        feat[b][c] = v;
        atomicMax(&smaxu[b], __float_as_uint(fabsf(v)));
    }
    __syncthreads();

    // roles for M accumulation: (b, J, hq): 4*10*8 = 320
    int bb = tid / 80;
    int r  = tid - bb * 80;
    int J  = r >> 3;
    int hq = r & 7;
    float4 acc = make_float4(0.f, 0.f, 0.f, 0.f);
    const float4* WcT4 = (const float4*)(WcT + i * 464 * 32);
    const float4* gp4  = (const float4*)(&Gp[bb * 10 + J][0]);

    for (int ch = 0; ch < 8; ++ch) {
        if (tid < 256) {  // compute g-powers for this 64-c chunk
            int b = tid >> 6, c = tid & 63;
            float g  = aff * feat[b][ch * 64 + c];
            float g2 = g * g;
            float p = g;
            Gp[b * 10 + 0][c] = p;
            #pragma unroll
            for (int j = 1; j < NJ; ++j) { p *= g2; Gp[b * 10 + j][c] = p; }
        }
        __syncthreads();
        #pragma unroll 4
        for (int c4 = 0; c4 < 16; ++c4) {
            float4 g4 = gp4[c4];
            int cbase = (ch * 64 + c4 * 4) * 8 + hq;  // float4 units: 8 float4 per c
            float4 w0 = WcT4[cbase];
            float4 w1 = WcT4[cbase + 8];
            float4 w2 = WcT4[cbase + 16];
            float4 w3 = WcT4[cbase + 24];
            FMA4(acc, g4.x, w0);
            FMA4(acc, g4.y, w1);
            FMA4(acc, g4.z, w2);
            FMA4(acc, g4.w, w3);
        }
        __syncthreads();
    }
    { // write M
        float4* m4 = (float4*)(&Mm[bb * 10 + J][hq * 4]);
        *m4 = acc;
    }
    __syncthreads();

    // epilogue: per (b,e) row
    const float4* M4base = (const float4*)(&Mm[0][0]);
    for (int task = tid; task < 4 * 150; task += 320) {
        int b = task / 150, e = task - b * 150;
        float s = feat[b][i * 150 + e];
        float gmax = fabsf(aff) * __uint_as_float(smaxu[b]);
        float a32[32];
        if (fabsf(s) * gmax <= X0f) {
            float wj[NJ];
            float s2 = s * s, p = s;
            wj[0] = pc.c[0] * p;
            #pragma unroll
            for (int j = 1; j < NJ; ++j) { p *= s2; wj[j] = pc.c[j] * p; }
            #pragma unroll
            for (int h4 = 0; h4 < 8; ++h4) {
                float4 a4 = make_float4(0.f, 0.f, 0.f, 0.f);
                #pragma unroll
                for (int j = 0; j < NJ; ++j) {
                    float4 m = M4base[(b * 10 + j) * 8 + h4];
                    FMA4(a4, wj[j], m);
                }
                a32[h4 * 4 + 0] = a4.x; a32[h4 * 4 + 1] = a4.y;
                a32[h4 * 4 + 2] = a4.z; a32[h4 * 4 + 3] = a4.w;
            }
        } else {
            // exact fallback for rare out-of-range rows
            #pragma unroll
            for (int h = 0; h < 32; ++h) a32[h] = 0.f;
            for (int c = 0; c < CAT; ++c) {
                float t = tanhf(s * aff * feat[b][c]);
                #pragma unroll
                for (int h4 = 0; h4 < 8; ++h4) {
                    float4 w = WcT4[c * 8 + h4];
                    a32[h4 * 4 + 0] = fmaf(t, w.x, a32[h4 * 4 + 0]);
                    a32[h4 * 4 + 1] = fmaf(t, w.y, a32[h4 * 4 + 1]);
                    a32[h4 * 4 + 2] = fmaf(t, w.z, a32[h4 * 4 + 2]);
                    a32[h4 * 4 + 3] = fmaf(t, w.w, a32[h4 * 4 + 3]);
                }
            }
        }
        float o = 0.f;
        #pragma unroll
        for (int h = 0; h < 32; ++h) {
            float Hh = fmaxf(fmaf(s, wW[h], a32[h]), 0.f);
            o = fmaf(Hh, wH[h], o);
        }
        wsFeats[(b0 + b) * ESTRIDE + i * 150 + e] = o + s;
    }
}

// ---------------- K3: classifier 450 -> 128 -> 7. 8 batch rows per block. ----------------
__global__ __launch_bounds__(256) void k_cls(
    const float* __restrict__ wsFeats,
    const float* __restrict__ W1T,   // [450][128]
    const float* __restrict__ b1,
    const float* __restrict__ W2,    // [7][128]
    const float* __restrict__ b2,
    float* __restrict__ out) {
    __shared__ float fs[8][ESTRIDE];
    __shared__ float hs[8][128];
    int tid = threadIdx.x;
    int b0 = blockIdx.x * 8;
    for (int idx = tid; idx < 8 * ESTRIDE; idx += 256) {
        int b = idx / ESTRIDE, c = idx - b * ESTRIDE;
        fs[b][c] = (c < CAT) ? wsFeats[(b0 + b) * ESTRIDE + c] : 0.f;
    }
    __syncthreads();
    {
        int b = tid >> 5, kq = tid & 31;
        const float4* w4 = (const float4*)W1T;
        float4 acc = ((const float4*)b1)[kq];
        #pragma unroll 4
        for (int c = 0; c < CAT; ++c) {
            float fv = fs[b][c];
            float4 w = w4[c * 32 + kq];
            FMA4(acc, fv, w);
        }
        *((float4*)&hs[b][kq * 4]) = acc;
    }
    __syncthreads();
    if (tid < 56) {
        int b = tid / 7, o = tid - (tid / 7) * 7;
        float acc = b2[o];
        #pragma unroll 8
        for (int k = 0; k < 128; ++k) acc = fmaf(hs[b][k], W2[o * 128 + k], acc);
        out[(b0 + b) * 7 + o] = acc;
    }
}

// ---------------- host: Chebyshev fit of tanh on [-3,3], degree-19 odd, monomial form ----------------
static void make_poly(float* cf) {
    const double a = 3.0;
    const int NQ = 128, DEG = 19;
    const double PI = 3.14159265358979323846;
    double b[DEG + 1];
    for (int k = 0; k <= DEG; ++k) b[k] = 0.0;
    for (int m = 0; m < NQ; ++m) {
        double th = PI * (m + 0.5) / NQ;
        double f = tanh(a * cos(th));
        for (int k = 1; k <= DEG; k += 2)
            b[k] += (2.0 / NQ) * f * cos(k * th);
    }
    double Tp[DEG + 1], Tc[DEG + 1], Tn[DEG + 1], mono[DEG + 1];
    for (int j = 0; j <= DEG; ++j) { Tp[j] = 0; Tc[j] = 0; mono[j] = 0; }
    Tp[0] = 1.0;  // T0
    Tc[1] = 1.0;  // T1
    for (int j = 0; j <= DEG; ++j) mono[j] += b[1] * Tc[j];
    for (int k = 2; k <= DEG; ++k) {
        for (int j = 0; j <= DEG; ++j) Tn[j] = -Tp[j];
        for (int j = 1; j <= DEG; ++j) Tn[j] += 2.0 * Tc[j - 1];
        for (int j = 0; j <= DEG; ++j) { Tp[j] = Tc[j]; Tc[j] = Tn[j]; }
        if (k & 1) for (int j = 0; j <= DEG; ++j) mono[j] += b[k] * Tc[j];
    }
    for (int J = 0; J < NJ; ++J) {
        int j = 2 * J + 1;
        cf[J] = (float)(mono[j] / pow(a, (double)j));
    }
}

extern "C" void kernel_launch(void* const* d_in, const int* in_sizes, int n_in,
                              void* d_out, int out_size, void* d_ws, size_t ws_size,
                              hipStream_t stream) {
    (void)in_sizes; (void)n_in; (void)out_size; (void)ws_size;
    const float* x0    = (const float*)d_in[0];
    const float* x1    = (const float*)d_in[1];
    const float* x2    = (const float*)d_in[2];
    const float* eW0   = (const float*)d_in[3];
    const float* eb0   = (const float*)d_in[4];
    const float* eW1   = (const float*)d_in[5];
    const float* eb1   = (const float*)d_in[6];
    const float* eW2   = (const float*)d_in[7];
    const float* eb2   = (const float*)d_in[8];
    const float* affw  = (const float*)d_in[9];
    const float* Ww    = (const float*)d_in[10];
    const float* Wc    = (const float*)d_in[11];
    const float* Wh    = (const float*)d_in[12];
    const float* cW1   = (const float*)d_in[13];
    const float* cb1   = (const float*)d_in[14];
    const float* cW2   = (const float*)d_in[15];
    const float* cb2   = (const float*)d_in[16];

    float* ws      = (float*)d_ws;
    float* wsEnc   = ws;                               // 2048*456
    float* wsFeats = wsEnc   + 2048 * ESTRIDE;         // 2048*456
    float* wsWcT   = wsFeats + 2048 * ESTRIDE;         // 3*464*32
    float* wsW1T   = wsWcT   + 3 * 464 * 32;           // 450*128

    Poly pc;
    make_poly(pc.c);

    k_repack<<<dim3(200), dim3(256), 0, stream>>>(Wc, cW1, wsWcT, wsW1T);
    k_enc<<<dim3(256), dim3(256), 0, stream>>>(x0, x1, x2, eW0, eb0, eW1, eb1, eW2, eb2, wsEnc);
    k_attn<<<dim3(512, 3), dim3(320), 0, stream>>>(wsEnc, wsWcT, affw, Ww, Wh, wsFeats, pc);
    k_cls<<<dim3(256), dim3(256), 0, stream>>>(wsFeats, wsW1T, cb1, cW2, cb2, (float*)d_out);
}

// Round 2
// 103.577 us; speedup vs baseline: 2.5647x; 2.5647x over previous
//
#include <hip/hip_runtime.h>
#include <math.h>

#define NJ 10        // odd powers x^1..x^19
#define X0f 3.0f
#define ESTR 456     // seg-padded feature stride: 3 segments x 152

struct Poly { float c[NJ]; };

#define FMA4(A,S,W) do { (A).x = fmaf((S),(W).x,(A).x); (A).y = fmaf((S),(W).y,(A).y); \
                         (A).z = fmaf((S),(W).z,(A).z); (A).w = fmaf((S),(W).w,(A).w); } while(0)

// ---------------- K0: repack all weights into coalesced/padded layouts ----------------
// WcT[i][m 0..455][32]   (m = seg*152+e', zero pad rows)
// W1T[m 0..455][128]
// Wt0[304][152], Wt1[76][152], Wt2[36][152]  (d-major, e-padded, zero pads)
__global__ __launch_bounds__(256) void k_repack(
    const float* __restrict__ Wc, const float* __restrict__ W1,
    const float* __restrict__ eW0, const float* __restrict__ eW1, const float* __restrict__ eW2,
    float* __restrict__ WcT, float* __restrict__ W1T,
    float* __restrict__ Wt0, float* __restrict__ Wt1, float* __restrict__ Wt2) {
    int tid = blockIdx.x * 256 + threadIdx.x;
    int stride = gridDim.x * 256;
    for (int idx = tid; idx < 3 * 456 * 32; idx += stride) {
        int i = idx / (456 * 32); int rem = idx - i * 456 * 32;
        int m = rem >> 5, h = rem & 31;
        int seg = m / 152, e = m - seg * 152;
        WcT[idx] = (e < 150) ? Wc[((size_t)i * 32 + h) * 450 + seg * 150 + e] : 0.f;
    }
    for (int idx = tid; idx < 456 * 128; idx += stride) {
        int m = idx >> 7, k = idx & 127;
        int seg = m / 152, e = m - seg * 152;
        W1T[idx] = (e < 150) ? W1[k * 450 + seg * 150 + e] : 0.f;
    }
    for (int idx = tid; idx < 304 * 152; idx += stride) {
        int d = idx / 152, e = idx - d * 152;
        Wt0[idx] = (d < 300 && e < 150) ? eW0[e * 300 + d] : 0.f;
    }
    for (int idx = tid; idx < 76 * 152; idx += stride) {
        int d = idx / 152, e = idx - d * 152;
        Wt1[idx] = (d < 74 && e < 150) ? eW1[e * 74 + d] : 0.f;
    }
    for (int idx = tid; idx < 36 * 152; idx += stride) {
        int d = idx / 152, e = idx - d * 152;
        Wt2[idx] = (d < 35 && e < 150) ? eW2[e * 35 + d] : 0.f;
    }
}

// ---------------- K1: encoders. grid (B/8, 3). roles (b, e4): coalesced Wt rows ----------------
__global__ __launch_bounds__(320) void k_enc(
    const float* __restrict__ x0, const float* __restrict__ x1, const float* __restrict__ x2,
    const float* __restrict__ eb0, const float* __restrict__ eb1, const float* __restrict__ eb2,
    const float* __restrict__ Wt0, const float* __restrict__ Wt1, const float* __restrict__ Wt2,
    float* __restrict__ wsEnc) {
    __shared__ __align__(16) float xs[8][304];
    int tid = threadIdx.x;
    int b0 = blockIdx.x * 8;
    int br = blockIdx.y;
    const float* xsrc = br == 0 ? x0 : br == 1 ? x1 : x2;
    const float* eb   = br == 0 ? eb0 : br == 1 ? eb1 : eb2;
    const float* Wt   = br == 0 ? Wt0 : br == 1 ? Wt1 : Wt2;
    int D   = br == 0 ? 300 : br == 1 ? 74 : 35;
    int DP4 = br == 0 ? 76  : br == 1 ? 19 : 9;
    int DP  = DP4 * 4;
    for (int idx = tid; idx < 8 * DP; idx += 320) {
        int b = idx / DP, d = idx - b * DP;
        xs[b][d] = (d < D) ? xsrc[(size_t)(b0 + b) * D + d] : 0.f;
    }
    __syncthreads();
    if (tid < 304) {
        int b = tid / 38, e4 = tid - (tid / 38) * 38;
        int e = e4 * 4;
        float4 acc;
        acc.x = eb[e]; acc.y = eb[e + 1];
        acc.z = (e + 2 < 150) ? eb[e + 2] : 0.f;
        acc.w = (e + 3 < 150) ? eb[e + 3] : 0.f;
        const float4* xrow = (const float4*)&xs[b][0];
        const float4* W4 = (const float4*)Wt + e4;
        for (int d4 = 0; d4 < DP4; ++d4) {
            float4 x4 = xrow[d4];
            float4 w0 = W4[(d4 * 4 + 0) * 38];
            float4 w1 = W4[(d4 * 4 + 1) * 38];
            float4 w2 = W4[(d4 * 4 + 2) * 38];
            float4 w3 = W4[(d4 * 4 + 3) * 38];
            FMA4(acc, x4.x, w0);
            FMA4(acc, x4.y, w1);
            FMA4(acc, x4.z, w2);
            FMA4(acc, x4.w, w3);
        }
        ((float4*)(wsEnc + (size_t)(b0 + b) * ESTR + br * 152))[e4] = acc;
    }
}

// ---------------- K2: attention branch, factorized tanh poly, register-blocked ----------------
// grid (B/8, 3), block 192. roles: slice=tid>>6 (c/e slice), bb=(tid>>3)&7, hq=tid&7.
__global__ __launch_bounds__(192) void k_attn(
    const float* __restrict__ wsEnc,
    const float* __restrict__ WcT,     // [3][456][32]
    const float* __restrict__ affw,
    const float* __restrict__ Ww,      // [3][32]
    const float* __restrict__ Wh,      // [3][32]
    float* __restrict__ wsFeats,
    Poly pc) {
    __shared__ __align__(16) float feat[8][468];    // 456 + zero pad; stride 468 spreads banks
    __shared__ float4 MpL[3 * 640];                 // partial M: [slice][bb][J][hq] float4
    __shared__ unsigned smaxu[8];

    int tid = threadIdx.x;
    int b0 = blockIdx.x * 8;
    int i = blockIdx.y;
    float aff = affw[i];
    int slice = tid >> 6;
    int lane = tid & 63;
    int bb = lane >> 3;
    int hq = lane & 7;

    if (tid < 8) smaxu[tid] = 0u;
    __syncthreads();
    for (int idx = tid; idx < 8 * 117; idx += 192) {
        int b = idx / 117, q = idx - b * 117;
        float4 v = (q < 114) ? ((const float4*)(wsEnc + (size_t)(b0 + b) * ESTR))[q]
                             : make_float4(0.f, 0.f, 0.f, 0.f);
        ((float4*)&feat[b][0])[q] = v;
        float mx = fmaxf(fmaxf(fabsf(v.x), fabsf(v.y)), fmaxf(fabsf(v.z), fabsf(v.w)));
        atomicMax(&smaxu[b], __float_as_uint(mx));
    }
    __syncthreads();

    // ---- M phase: thread owns M[bb][0..9][hq*4..+3] over its 152-c slice ----
    const float4* Wb4 = (const float4*)WcT + (size_t)i * 456 * 8 + hq;
    const float4* frow = (const float4*)&feat[bb][0];
    float4 acc[NJ];
    #pragma unroll
    for (int J = 0; J < NJ; ++J) acc[J] = make_float4(0.f, 0.f, 0.f, 0.f);
    int m4lo = slice * 38, m4hi = m4lo + 38;
    for (int m4 = m4lo; m4 < m4hi; ++m4) {
        float4 f4 = frow[m4];
        #pragma unroll
        for (int r = 0; r < 4; ++r) {
            float fv = (r == 0) ? f4.x : (r == 1) ? f4.y : (r == 2) ? f4.z : f4.w;
            float g = aff * fv;
            float g2 = g * g;
            float4 w = Wb4[(m4 * 4 + r) * 8];
            float p = g;
            FMA4(acc[0], p, w);
            #pragma unroll
            for (int J = 1; J < NJ; ++J) { p *= g2; FMA4(acc[J], p, w); }
        }
    }
    #pragma unroll
    for (int J = 0; J < NJ; ++J)
        MpL[((slice * 8 + bb) * 10 + J) * 8 + hq] = acc[J];
    __syncthreads();

    // ---- reduce slices + fold poly coefficient cJ into M ----
    for (int v = tid; v < 640; v += 192) {
        float4 a = MpL[v], b = MpL[v + 640], c = MpL[v + 1280];
        int J = (v >> 3) % 10;
        float s = pc.c[J];
        float4 o;
        o.x = (a.x + b.x + c.x) * s; o.y = (a.y + b.y + c.y) * s;
        o.z = (a.z + b.z + c.z) * s; o.w = (a.w + b.w + c.w) * s;
        MpL[v] = o;
    }
    __syncthreads();

    // ---- epilogue: thread (slice e-range, bb, hq); M + weights in registers ----
    float4 Mreg[NJ];
    #pragma unroll
    for (int J = 0; J < NJ; ++J) Mreg[J] = MpL[(bb * 10 + J) * 8 + hq];
    float4 wW4 = ((const float4*)(Ww + i * 32))[hq];
    float4 wH4 = ((const float4*)(Wh + i * 32))[hq];
    float gmax = fabsf(aff) * __uint_as_float(smaxu[bb]);
    int e4lo = (slice == 0) ? 0 : (slice == 1) ? 13 : 26;
    int e4hi = (slice == 0) ? 13 : (slice == 1) ? 26 : 38;
    int colq = i * 38;  // (i*152)/4
    for (int e4 = e4lo; e4 < e4hi; ++e4) {
        float4 s4 = frow[colq + e4];
        float ores[4];
        #pragma unroll
        for (int r = 0; r < 4; ++r) {
            float s = (r == 0) ? s4.x : (r == 1) ? s4.y : (r == 2) ? s4.z : s4.w;
            float4 a4;
            if (fabsf(s) * gmax <= X0f) {
                float s2 = s * s, p = s;
                a4.x = Mreg[0].x * p; a4.y = Mreg[0].y * p;
                a4.z = Mreg[0].z * p; a4.w = Mreg[0].w * p;
                #pragma unroll
                for (int J = 1; J < NJ; ++J) { p *= s2; FMA4(a4, p, Mreg[J]); }
            } else {
                a4 = make_float4(0.f, 0.f, 0.f, 0.f);
                for (int m = 0; m < 456; ++m) {
                    float t = tanhf(s * aff * feat[bb][m]);
                    float4 w = Wb4[m * 8];
                    FMA4(a4, t, w);
                }
            }
            float hx = fmaxf(fmaf(s, wW4.x, a4.x), 0.f);
            float hy = fmaxf(fmaf(s, wW4.y, a4.y), 0.f);
            float hz = fmaxf(fmaf(s, wW4.z, a4.z), 0.f);
            float hw = fmaxf(fmaf(s, wW4.w, a4.w), 0.f);
            float csum = hx * wH4.x + hy * wH4.y + hz * wH4.z + hw * wH4.w;
            csum += __shfl_xor(csum, 1);
            csum += __shfl_xor(csum, 2);
            csum += __shfl_xor(csum, 4);
            ores[r] = csum + s;
        }
        if (hq == 0) {
            float4 outv = make_float4(ores[0], ores[1], ores[2], ores[3]);
            ((float4*)(wsFeats + (size_t)(b0 + bb) * ESTR))[colq + e4] = outv;
        }
    }
}

// ---------------- K3: classifier 456 -> 128 -> 7. grid B/8, block 256 ----------------
__global__ __launch_bounds__(256) void k_cls(
    const float* __restrict__ wsFeats,
    const float* __restrict__ W1T,   // [456][128]
    const float* __restrict__ b1,
    const float* __restrict__ W2,    // [7][128]
    const float* __restrict__ b2,
    float* __restrict__ out) {
    __shared__ __align__(16) float fs[8][ESTR];
    __shared__ __align__(16) float hs[8][132];
    int tid = threadIdx.x;
    int b0 = blockIdx.x * 8;
    for (int idx = tid; idx < 8 * 114; idx += 256) {
        int b = idx / 114, q = idx - b * 114;
        ((float4*)&fs[b][0])[q] = ((const float4*)(wsFeats + (size_t)(b0 + b) * ESTR))[q];
    }
    __syncthreads();
    {
        int b = tid >> 5, kq = tid & 31;
        float4 acc = ((const float4*)b1)[kq];
        const float4* W4 = (const float4*)W1T + kq;
        const float4* f4 = (const float4*)&fs[b][0];
        for (int c4 = 0; c4 < 114; ++c4) {
            float4 fv = f4[c4];
            float4 w0 = W4[(c4 * 4 + 0) * 32];
            float4 w1 = W4[(c4 * 4 + 1) * 32];
            float4 w2 = W4[(c4 * 4 + 2) * 32];
            float4 w3 = W4[(c4 * 4 + 3) * 32];
            FMA4(acc, fv.x, w0);
            FMA4(acc, fv.y, w1);
            FMA4(acc, fv.z, w2);
            FMA4(acc, fv.w, w3);
        }
        *((float4*)&hs[b][kq * 4]) = acc;
    }
    __syncthreads();
    if (tid < 56) {
        int b = tid / 7, o = tid - (tid / 7) * 7;
        const float4* h4 = (const float4*)&hs[b][0];
        const float4* w4 = (const float4*)(W2 + o * 128);
        float4 a4 = make_float4(0.f, 0.f, 0.f, 0.f);
        #pragma unroll 8
        for (int k4 = 0; k4 < 32; ++k4) {
            float4 h = h4[k4], w = w4[k4];
            a4.x = fmaf(h.x, w.x, a4.x); a4.y = fmaf(h.y, w.y, a4.y);
            a4.z = fmaf(h.z, w.z, a4.z); a4.w = fmaf(h.w, w.w, a4.w);
        }
        out[(size_t)(b0 + b) * 7 + o] = b2[o] + a4.x + a4.y + a4.z + a4.w;
    }
}

// ---------------- host: Chebyshev fit of tanh on [-3,3], degree-19 odd, monomial form ----------------
static void make_poly(float* cf) {
    const double a = 3.0;
    const int NQ = 128, DEG = 19;
    const double PI = 3.14159265358979323846;
    double b[DEG + 1];
    for (int k = 0; k <= DEG; ++k) b[k] = 0.0;
    for (int m = 0; m < NQ; ++m) {
        double th = PI * (m + 0.5) / NQ;
        double f = tanh(a * cos(th));
        for (int k = 1; k <= DEG; k += 2)
            b[k] += (2.0 / NQ) * f * cos(k * th);
    }
    double Tp[DEG + 1], Tc[DEG + 1], Tn[DEG + 1], mono[DEG + 1];
    for (int j = 0; j <= DEG; ++j) { Tp[j] = 0; Tc[j] = 0; mono[j] = 0; }
    Tp[0] = 1.0;
    Tc[1] = 1.0;
    for (int j = 0; j <= DEG; ++j) mono[j] += b[1] * Tc[j];
    for (int k = 2; k <= DEG; ++k) {
        for (int j = 0; j <= DEG; ++j) Tn[j] = -Tp[j];
        for (int j = 1; j <= DEG; ++j) Tn[j] += 2.0 * Tc[j - 1];
        for (int j = 0; j <= DEG; ++j) { Tp[j] = Tc[j]; Tc[j] = Tn[j]; }
        if (k & 1) for (int j = 0; j <= DEG; ++j) mono[j] += b[k] * Tc[j];
    }
    for (int J = 0; J < NJ; ++J) {
        int j = 2 * J + 1;
        cf[J] = (float)(mono[j] / pow(a, (double)j));
    }
}

extern "C" void kernel_launch(void* const* d_in, const int* in_sizes, int n_in,
                              void* d_out, int out_size, void* d_ws, size_t ws_size,
                              hipStream_t stream) {
    (void)in_sizes; (void)n_in; (void)out_size; (void)ws_size;
    const float* x0    = (const float*)d_in[0];
    const float* x1    = (const float*)d_in[1];
    const float* x2    = (const float*)d_in[2];
    const float* eW0   = (const float*)d_in[3];
    const float* eb0   = (const float*)d_in[4];
    const float* eW1   = (const float*)d_in[5];
    const float* eb1   = (const float*)d_in[6];
    const float* eW2   = (const float*)d_in[7];
    const float* eb2   = (const float*)d_in[8];
    const float* affw  = (const float*)d_in[9];
    const float* Ww    = (const float*)d_in[10];
    const float* Wc    = (const float*)d_in[11];
    const float* Wh    = (const float*)d_in[12];
    const float* cW1   = (const float*)d_in[13];
    const float* cb1   = (const float*)d_in[14];
    const float* cW2   = (const float*)d_in[15];
    const float* cb2   = (const float*)d_in[16];

    float* ws      = (float*)d_ws;
    float* wsEnc   = ws;                         // 2048*456
    float* wsFeats = ws + 933888;                // 2048*456
    float* wsWcT   = ws + 1867776;               // 3*456*32
    float* wsW1T   = ws + 1911552;               // 456*128
    float* wsWt0   = ws + 1969920;               // 304*152
    float* wsWt1   = ws + 2016128;               // 76*152
    float* wsWt2   = ws + 2027680;               // 36*152

    Poly pc;
    make_poly(pc.c);

    k_repack<<<dim3(160), dim3(256), 0, stream>>>(Wc, cW1, eW0, eW1, eW2,
                                                  wsWcT, wsW1T, wsWt0, wsWt1, wsWt2);
    k_enc<<<dim3(256, 3), dim3(320), 0, stream>>>(x0, x1, x2, eb0, eb1, eb2,
                                                  wsWt0, wsWt1, wsWt2, wsEnc);
    k_attn<<<dim3(256, 3), dim3(192), 0, stream>>>(wsEnc, wsWcT, affw, Ww, Wh, wsFeats, pc);
    k_cls<<<dim3(256), dim3(256), 0, stream>>>(wsFeats, wsW1T, cb1, cW2, cb2, (float*)d_out);
}

// Round 3
// 77.112 us; speedup vs baseline: 3.4448x; 1.3432x over previous
//
#include <hip/hip_runtime.h>
#include <math.h>

#define NJ 9         // odd powers x^1..x^17
#define DEG 17
#define X0f 3.0f

struct Poly { float c[NJ]; };

#define FMA4(A,S,W) do { (A).x = fmaf((S),(W).x,(A).x); (A).y = fmaf((S),(W).y,(A).y); \
                         (A).z = fmaf((S),(W).z,(A).z); (A).w = fmaf((S),(W).w,(A).w); } while(0)

// ---------------- K0: repack weights ----------------
// WcT[i][m 0..463][32]  (m = seg*152+e', zero pads; rows 456..463 zero)
// W1T[m 0..455][128]
// Wt0[304][152], Wt1[76][152], Wt2[36][152]  (d-major, e-padded, zero pads)
__global__ __launch_bounds__(256) void k_repack(
    const float* __restrict__ Wc, const float* __restrict__ W1,
    const float* __restrict__ eW0, const float* __restrict__ eW1, const float* __restrict__ eW2,
    float* __restrict__ WcT, float* __restrict__ W1T,
    float* __restrict__ Wt0, float* __restrict__ Wt1, float* __restrict__ Wt2) {
    int tid = blockIdx.x * 256 + threadIdx.x;
    int stride = gridDim.x * 256;
    for (int idx = tid; idx < 3 * 464 * 32; idx += stride) {
        int i = idx / (464 * 32); int rem = idx - i * 464 * 32;
        int m = rem >> 5, h = rem & 31;
        float v = 0.f;
        if (m < 456) {
            int seg = m / 152, e = m - seg * 152;
            if (e < 150) v = Wc[((size_t)i * 32 + h) * 450 + seg * 150 + e];
        }
        WcT[idx] = v;
    }
    for (int idx = tid; idx < 456 * 128; idx += stride) {
        int m = idx >> 7, k = idx & 127;
        int seg = m / 152, e = m - seg * 152;
        W1T[idx] = (e < 150) ? W1[k * 450 + seg * 150 + e] : 0.f;
    }
    for (int idx = tid; idx < 304 * 152; idx += stride) {
        int d = idx / 152, e = idx - d * 152;
        Wt0[idx] = (d < 300 && e < 150) ? eW0[e * 300 + d] : 0.f;
    }
    for (int idx = tid; idx < 76 * 152; idx += stride) {
        int d = idx / 152, e = idx - d * 152;
        Wt1[idx] = (d < 74 && e < 150) ? eW1[e * 74 + d] : 0.f;
    }
    for (int idx = tid; idx < 36 * 152; idx += stride) {
        int d = idx / 152, e = idx - d * 152;
        Wt2[idx] = (d < 35 && e < 150) ? eW2[e * 35 + d] : 0.f;
    }
}

// ---------------- K1: fully fused enc -> attn -> cls. grid 256, block 768 ----------------
__global__ __launch_bounds__(768, 1) void k_fused(
    const float* __restrict__ x0, const float* __restrict__ x1, const float* __restrict__ x2,
    const float* __restrict__ eb0, const float* __restrict__ eb1, const float* __restrict__ eb2,
    const float* __restrict__ Wt0, const float* __restrict__ Wt1, const float* __restrict__ Wt2,
    const float* __restrict__ WcT,
    const float* __restrict__ affw, const float* __restrict__ Ww, const float* __restrict__ Wh,
    const float* __restrict__ W1T, const float* __restrict__ cb1,
    const float* __restrict__ cW2, const float* __restrict__ cb2,
    float* __restrict__ out, Poly pc) {
    __shared__ __align__(16) float xs[8][428];   // seg0 @0 (304), seg1 @304 (76), seg2 @380 (36)
    __shared__ __align__(16) float feat[8][468]; // enc outputs, 464 valid (456 data + zeros), later reused for hs
    __shared__ __align__(16) float fo[8][468];   // attn outputs (cls input)
    __shared__ unsigned smaxu[8];

    int tid = threadIdx.x;
    int b0 = blockIdx.x * 8;

    // ---- P0: stage x, init ----
    if (tid < 8) smaxu[tid] = 0u;
    if (tid < 64) feat[tid >> 3][456 + (tid & 7)] = 0.f;
    for (int idx = tid; idx < 8 * 304; idx += 768) {
        int b = idx / 304, d = idx - b * 304;
        xs[b][d] = (d < 300) ? x0[(size_t)(b0 + b) * 300 + d] : 0.f;
    }
    for (int idx = tid; idx < 8 * 76; idx += 768) {
        int b = idx / 76, d = idx - b * 76;
        xs[b][304 + d] = (d < 74) ? x1[(size_t)(b0 + b) * 74 + d] : 0.f;
    }
    for (int idx = tid; idx < 8 * 36; idx += 768) {
        int b = idx / 36, d = idx - b * 36;
        xs[b][380 + d] = (d < 35) ? x2[(size_t)(b0 + b) * 35 + d] : 0.f;
    }
    __syncthreads();

    // ---- P1: encoders. task = (b = t&7, m4 = t>>3), 912 tasks ----
    {
        int tasks[2]; int nt = 1;
        tasks[0] = tid;
        if (tid >= 624) { tasks[nt++] = 768 + (767 - tid); }
        for (int q = 0; q < nt; ++q) {
            int task = tasks[q];
            int b = task & 7, m4 = task >> 3;
            int seg = (m4 >= 76) ? 2 : (m4 >= 38) ? 1 : 0;
            int e4 = m4 - seg * 38;
            const float* eb = seg == 0 ? eb0 : seg == 1 ? eb1 : eb2;
            const float4* Wt4 = (const float4*)(seg == 0 ? Wt0 : seg == 1 ? Wt1 : Wt2) + e4;
            const float4* xr = (const float4*)&xs[b][seg == 0 ? 0 : seg == 1 ? 304 : 380];
            int DP4 = seg == 0 ? 76 : seg == 1 ? 19 : 9;
            int e = e4 * 4;
            float4 acc;
            acc.x = (e     < 150) ? eb[e]     : 0.f;
            acc.y = (e + 1 < 150) ? eb[e + 1] : 0.f;
            acc.z = (e + 2 < 150) ? eb[e + 2] : 0.f;
            acc.w = (e + 3 < 150) ? eb[e + 3] : 0.f;
            for (int d4 = 0; d4 < DP4; ++d4) {
                float4 x4 = xr[d4];
                float4 w0 = Wt4[(d4 * 4 + 0) * 38];
                float4 w1 = Wt4[(d4 * 4 + 1) * 38];
                float4 w2 = Wt4[(d4 * 4 + 2) * 38];
                float4 w3 = Wt4[(d4 * 4 + 3) * 38];
                FMA4(acc, x4.x, w0);
                FMA4(acc, x4.y, w1);
                FMA4(acc, x4.z, w2);
                FMA4(acc, x4.w, w3);
            }
            ((float4*)&feat[b][0])[m4] = acc;
            float mx = fmaxf(fmaxf(fabsf(acc.x), fabsf(acc.y)), fmaxf(fabsf(acc.z), fabsf(acc.w)));
            atomicMax(&smaxu[b], __float_as_uint(mx));
        }
    }
    __syncthreads();

    // ---- P2: attention. wave w: branch i = w>>2; lane = hq(3b)|slice(2b)|bhalf(1b) ----
    {
        int w = tid >> 6;
        int i = w >> 2;
        int wp = w & 3;
        int lane = tid & 63;
        int hq = lane & 7, slice = (lane >> 3) & 3, bh = lane >> 5;
        int b = wp * 2 + bh;
        float aff = affw[i];
        const float4* Wb4 = (const float4*)WcT + (size_t)i * 464 * 8 + hq;
        const float4* frow = (const float4*)&feat[b][0];

        float4 acc[NJ];
        #pragma unroll
        for (int J = 0; J < NJ; ++J) acc[J] = make_float4(0.f, 0.f, 0.f, 0.f);

        int m4lo = slice * 29, m4hi = m4lo + 29;
        for (int m4 = m4lo; m4 < m4hi; ++m4) {
            float4 f4 = frow[m4];
            #pragma unroll
            for (int r = 0; r < 4; ++r) {
                float fv = (r == 0) ? f4.x : (r == 1) ? f4.y : (r == 2) ? f4.z : f4.w;
                float g = aff * fv;
                float g2 = g * g;
                float4 wv = Wb4[(m4 * 4 + r) * 8];
                float p = g;
                FMA4(acc[0], p, wv);
                #pragma unroll
                for (int J = 1; J < NJ; ++J) { p *= g2; FMA4(acc[J], p, wv); }
            }
        }
        // reduce across slice (lane bits 3,4), fold poly coeff
        #pragma unroll
        for (int J = 0; J < NJ; ++J) {
            float cJ = pc.c[J];
            float vx = acc[J].x; vx += __shfl_xor(vx, 8); vx += __shfl_xor(vx, 16);
            float vy = acc[J].y; vy += __shfl_xor(vy, 8); vy += __shfl_xor(vy, 16);
            float vz = acc[J].z; vz += __shfl_xor(vz, 8); vz += __shfl_xor(vz, 16);
            float vw = acc[J].w; vw += __shfl_xor(vw, 8); vw += __shfl_xor(vw, 16);
            acc[J].x = vx * cJ; acc[J].y = vy * cJ; acc[J].z = vz * cJ; acc[J].w = vw * cJ;
        }

        // epilogue
        float4 wW4 = ((const float4*)(Ww + i * 32))[hq];
        float4 wH4 = ((const float4*)(Wh + i * 32))[hq];
        float gmax = fabsf(aff) * __uint_as_float(smaxu[b]);
        int e4lo = slice * 10;
        int e4hi = (slice == 3) ? 38 : (e4lo + 10);
        for (int e4 = e4lo; e4 < e4hi; ++e4) {
            float4 s4 = frow[i * 38 + e4];
            float ores[4];
            #pragma unroll
            for (int r = 0; r < 4; ++r) {
                float s = (r == 0) ? s4.x : (r == 1) ? s4.y : (r == 2) ? s4.z : s4.w;
                float4 a4;
                if (fabsf(s) * gmax <= X0f) {
                    float s2 = s * s, p = s;
                    a4.x = acc[0].x * p; a4.y = acc[0].y * p;
                    a4.z = acc[0].z * p; a4.w = acc[0].w * p;
                    #pragma unroll
                    for (int J = 1; J < NJ; ++J) { p *= s2; FMA4(a4, p, acc[J]); }
                } else {
                    a4 = make_float4(0.f, 0.f, 0.f, 0.f);
                    for (int c = 0; c < 456; ++c) {
                        float t = tanhf(s * aff * feat[b][c]);
                        float4 wv = Wb4[c * 8];
                        FMA4(a4, t, wv);
                    }
                }
                float hx = fmaxf(fmaf(s, wW4.x, a4.x), 0.f);
                float hy = fmaxf(fmaf(s, wW4.y, a4.y), 0.f);
                float hz = fmaxf(fmaf(s, wW4.z, a4.z), 0.f);
                float hw = fmaxf(fmaf(s, wW4.w, a4.w), 0.f);
                float csum = hx * wH4.x + hy * wH4.y + hz * wH4.z + hw * wH4.w;
                csum += __shfl_xor(csum, 1);
                csum += __shfl_xor(csum, 2);
                csum += __shfl_xor(csum, 4);
                ores[r] = csum + s;
            }
            if (hq == 0)
                ((float4*)&fo[b][0])[i * 38 + e4] = make_float4(ores[0], ores[1], ores[2], ores[3]);
        }
    }
    __syncthreads();

    // ---- P3: classifier. part 1: h partials. roles cs = tid>>8, b = (tid>>5)&7, k4 = tid&31 ----
    {
        int cs = tid >> 8;
        int rr = tid & 255;
        int b = rr >> 5, k4 = rr & 31;
        const float4* W14 = (const float4*)W1T + k4;
        const float4* fr = (const float4*)&fo[b][0];
        float4 a = make_float4(0.f, 0.f, 0.f, 0.f);
        int c4lo = cs * 38, c4hi = c4lo + 38;
        for (int c4 = c4lo; c4 < c4hi; ++c4) {
            float4 fv = fr[c4];
            float4 w0 = W14[(c4 * 4 + 0) * 32];
            float4 w1 = W14[(c4 * 4 + 1) * 32];
            float4 w2 = W14[(c4 * 4 + 2) * 32];
            float4 w3 = W14[(c4 * 4 + 3) * 32];
            FMA4(a, fv.x, w0);
            FMA4(a, fv.y, w1);
            FMA4(a, fv.z, w2);
            FMA4(a, fv.w, w3);
        }
        ((float4*)&xs[0][0])[(cs * 8 + b) * 33 + k4] = a;  // xs reused as hpart
    }
    __syncthreads();
    if (tid < 256) {
        int b = tid >> 5, k4 = tid & 31;
        const float4* hp4 = (const float4*)&xs[0][0];
        float4 a = hp4[(b) * 33 + k4];
        float4 p1 = hp4[(8 + b) * 33 + k4];
        float4 p2 = hp4[(16 + b) * 33 + k4];
        float4 bias = ((const float4*)cb1)[k4];
        a.x += p1.x + p2.x + bias.x;
        a.y += p1.y + p2.y + bias.y;
        a.z += p1.z + p2.z + bias.z;
        a.w += p1.w + p2.w + bias.w;
        ((float4*)&feat[b][0])[k4] = a;  // feat row reused as hs[128]
    }
    __syncthreads();
    if (tid < 56) {
        int b = tid / 7, o = tid - (tid / 7) * 7;
        const float4* h4 = (const float4*)&feat[b][0];
        const float4* w4 = (const float4*)(cW2 + o * 128);
        float4 a4 = make_float4(0.f, 0.f, 0.f, 0.f);
        #pragma unroll 8
        for (int k4 = 0; k4 < 32; ++k4) {
            float4 h = h4[k4], w = w4[k4];
            a4.x = fmaf(h.x, w.x, a4.x); a4.y = fmaf(h.y, w.y, a4.y);
            a4.z = fmaf(h.z, w.z, a4.z); a4.w = fmaf(h.w, w.w, a4.w);
        }
        out[(size_t)(b0 + b) * 7 + o] = cb2[o] + a4.x + a4.y + a4.z + a4.w;
    }
}

// ---------------- host: Chebyshev fit of tanh on [-3,3], odd monomials ----------------
static void make_poly(float* cf) {
    const double a = 3.0;
    const int NQ = 128;
    const double PI = 3.14159265358979323846;
    double b[DEG + 1];
    for (int k = 0; k <= DEG; ++k) b[k] = 0.0;
    for (int m = 0; m < NQ; ++m) {
        double th = PI * (m + 0.5) / NQ;
        double f = tanh(a * cos(th));
        for (int k = 1; k <= DEG; k += 2)
            b[k] += (2.0 / NQ) * f * cos(k * th);
    }
    double Tp[DEG + 1], Tc[DEG + 1], Tn[DEG + 1], mono[DEG + 1];
    for (int j = 0; j <= DEG; ++j) { Tp[j] = 0; Tc[j] = 0; mono[j] = 0; }
    Tp[0] = 1.0;
    Tc[1] = 1.0;
    for (int j = 0; j <= DEG; ++j) mono[j] += b[1] * Tc[j];
    for (int k = 2; k <= DEG; ++k) {
        for (int j = 0; j <= DEG; ++j) Tn[j] = -Tp[j];
        for (int j = 1; j <= DEG; ++j) Tn[j] += 2.0 * Tc[j - 1];
        for (int j = 0; j <= DEG; ++j) { Tp[j] = Tc[j]; Tc[j] = Tn[j]; }
        if (k & 1) for (int j = 0; j <= DEG; ++j) mono[j] += b[k] * Tc[j];
    }
    for (int J = 0; J < NJ; ++J) {
        int j = 2 * J + 1;
        cf[J] = (float)(mono[j] / pow(a, (double)j));
    }
}

extern "C" void kernel_launch(void* const* d_in, const int* in_sizes, int n_in,
                              void* d_out, int out_size, void* d_ws, size_t ws_size,
                              hipStream_t stream) {
    (void)in_sizes; (void)n_in; (void)out_size; (void)ws_size;
    const float* x0    = (const float*)d_in[0];
    const float* x1    = (const float*)d_in[1];
    const float* x2    = (const float*)d_in[2];
    const float* eW0   = (const float*)d_in[3];
    const float* eb0   = (const float*)d_in[4];
    const float* eW1   = (const float*)d_in[5];
    const float* eb1   = (const float*)d_in[6];
    const float* eW2   = (const float*)d_in[7];
    const float* eb2   = (const float*)d_in[8];
    const float* affw  = (const float*)d_in[9];
    const float* Ww    = (const float*)d_in[10];
    const float* Wc    = (const float*)d_in[11];
    const float* Wh    = (const float*)d_in[12];
    const float* cW1   = (const float*)d_in[13];
    const float* cb1   = (const float*)d_in[14];
    const float* cW2   = (const float*)d_in[15];
    const float* cb2   = (const float*)d_in[16];

    float* ws    = (float*)d_ws;
    float* wsWcT = ws;                 // 3*464*32  = 44544
    float* wsW1T = ws + 44544;         // 456*128   = 58368
    float* wsWt0 = ws + 102912;        // 304*152   = 46208
    float* wsWt1 = ws + 149120;        // 76*152    = 11552
    float* wsWt2 = ws + 160672;        // 36*152    = 5472

    Poly pc;
    make_poly(pc.c);

    k_repack<<<dim3(96), dim3(256), 0, stream>>>(Wc, cW1, eW0, eW1, eW2,
                                                 wsWcT, wsW1T, wsWt0, wsWt1, wsWt2);
    k_fused<<<dim3(256), dim3(768), 0, stream>>>(x0, x1, x2, eb0, eb1, eb2,
                                                 wsWt0, wsWt1, wsWt2, wsWcT,
                                                 affw, Ww, Wh, wsW1T, cb1, cW2, cb2,
                                                 (float*)d_out, pc);
}